// Round 9
// baseline (269.074 us; speedup 1.0000x reference)
//
#include <hip/hip_runtime.h>

typedef __bf16 bf16x8 __attribute__((ext_vector_type(8)));
typedef float f32x4 __attribute__((ext_vector_type(4)));
typedef unsigned int u32x4 __attribute__((ext_vector_type(4)));

typedef const void __attribute__((address_space(1)))* gas1;
typedef void __attribute__((address_space(3)))* las3;

__device__ __forceinline__ unsigned short f2bf(float f) {
  unsigned int u = __builtin_bit_cast(unsigned int, f);
  u += 0x7fffu + ((u >> 16) & 1u);   // RNE
  return (unsigned short)(u >> 16);
}
__device__ __forceinline__ float bf2f(unsigned short h) {
  unsigned int u = ((unsigned int)h) << 16;
  return __builtin_bit_cast(float, u);
}
__device__ __forceinline__ unsigned int pack2bf(float lo, float hi) {
  return (unsigned int)f2bf(lo) | ((unsigned int)f2bf(hi) << 16);
}
// truncating pack (P in [0,1])
__device__ __forceinline__ unsigned int packtr(float lo, float hi) {
  return __builtin_amdgcn_perm(__builtin_bit_cast(unsigned int, hi),
                               __builtin_bit_cast(unsigned int, lo), 0x07060302u);
}

// ---------------- fused prep: x->bf16 + 4 weight transposes + packed sin/cos ----------
// grid 7168: [0,4096) cvt x; [4096,5120) wq^T; [5120,5376) wk^T; [5376,5632) wv^T;
// [5632,6656) wo^T; [6656,7168) scT[s][i] = {sin,cos}.
__global__ __launch_bounds__(256) void prep(const float* __restrict__ x,
                                            const float* __restrict__ wq,
                                            const float* __restrict__ wk,
                                            const float* __restrict__ wv,
                                            const float* __restrict__ wo,
                                            const float* __restrict__ sinT,
                                            const float* __restrict__ cosT,
                                            unsigned short* __restrict__ xb,
                                            unsigned short* __restrict__ wtqkv,
                                            unsigned short* __restrict__ wot,
                                            float2* __restrict__ scT) {
  __shared__ float tile[32][33];
  const int b = blockIdx.x;
  const int tid = threadIdx.x;
  if (b < 4096) {
    int i = b * 256 + tid;
    float4 v = ((const float4*)x)[i];
    uint2 o;
    o.x = pack2bf(v.x, v.y);
    o.y = pack2bf(v.z, v.w);
    ((uint2*)xb)[i] = o;
    return;
  }
  if (b >= 6656) {
    int idx = (b - 6656) * 256 + tid;    // 131072 = 4096*32
    scT[idx] = make_float2(sinT[idx], cosT[idx]);
    return;
  }
  const float* src;
  unsigned short* dst;
  int R, C, t;
  if (b < 5120)      { t = b - 4096; src = wq; dst = wtqkv;               R = 1024; C = 1024; }
  else if (b < 5376) { t = b - 5120; src = wk; dst = wtqkv + 1024 * 1024; R = 1024; C = 256; }
  else if (b < 5632) { t = b - 5376; src = wv; dst = wtqkv + 1280 * 1024; R = 1024; C = 256; }
  else               { t = b - 5632; src = wo; dst = wot;                 R = 1024; C = 1024; }
  const int ntc = C >> 5;
  const int c0 = (t % ntc) * 32, r0 = (t / ntc) * 32;
  const int tx = tid & 31, ty = tid >> 5;
#pragma unroll
  for (int i = 0; i < 4; ++i)
    tile[ty + i * 8][tx] = src[(r0 + ty + i * 8) * C + c0 + tx];
  __syncthreads();
#pragma unroll
  for (int i = 0; i < 4; ++i)
    dst[(c0 + ty + i * 8) * R + r0 + tx] = f2bf(tile[tx][ty + i * 8]);
}

// ---------------- QKV GEMM: 128x64 tile (3 blocks/CU), m97 2-barrier, rope epilogue ---
// grid (24, 32). n-tiles: 0..15 Q, 16..19 K, 20..23 V.
__global__ __launch_bounds__(256, 3) void gemm_qkv(const unsigned short* __restrict__ A,
                                                   const unsigned short* __restrict__ Bt,
                                                   const float2* __restrict__ scT,
                                                   unsigned short* __restrict__ Qh,
                                                   unsigned short* __restrict__ Kh,
                                                   unsigned short* __restrict__ Vt) {
  __shared__ __align__(16) unsigned short Als[128 * 32];
  __shared__ __align__(16) unsigned short Bls[64 * 32];
  const int K = 1024;
  const int tid = threadIdx.x;
  const int wave = tid >> 6, lane = tid & 63;
  const int lgrp = lane >> 4, lmod = lane & 15;
  const int wm = (wave & 1) * 64, wn = (wave >> 1) * 32;
  const int m0 = blockIdx.y * 128, n0 = blockIdx.x * 64;
  const int rr = tid >> 2, cc = (tid & 3) * 8;

  f32x4 acc[4][2] = {};

  for (int k0 = 0; k0 < K; k0 += 32) {
    __syncthreads();
#pragma unroll
    for (int it = 0; it < 2; ++it) {
      int idx = tid + it * 256;
      __builtin_amdgcn_global_load_lds((gas1)(const void*)&A[(size_t)(m0 + (idx >> 2)) * K + k0 + cc],
                                       (las3)(void*)&Als[(it * 256 + wave * 64) * 8], 16, 0, 0);
    }
    __builtin_amdgcn_global_load_lds((gas1)(const void*)&Bt[(size_t)(n0 + rr) * K + k0 + cc],
                                     (las3)(void*)&Bls[(wave * 64) * 8], 16, 0, 0);
    __syncthreads();
    bf16x8 af[4], bfr[2];
#pragma unroll
    for (int mi = 0; mi < 4; ++mi)
      af[mi] = __builtin_bit_cast(bf16x8, *(const u32x4*)&Als[(wm + mi * 16 + lmod) * 32 + lgrp * 8]);
#pragma unroll
    for (int ni = 0; ni < 2; ++ni)
      bfr[ni] = __builtin_bit_cast(bf16x8, *(const u32x4*)&Bls[(wn + ni * 16 + lmod) * 32 + lgrp * 8]);
#pragma unroll
    for (int mi = 0; mi < 4; ++mi)
#pragma unroll
      for (int ni = 0; ni < 2; ++ni)
        acc[mi][ni] = __builtin_amdgcn_mfma_f32_16x16x32_bf16(af[mi], bfr[ni], acc[mi][ni], 0, 0, 0);
  }

  const int cbase = n0;                 // 64-aligned; wave col offset = wn
  if (cbase >= 1280) {
    const int kvh = (cbase - 1280) >> 6;
#pragma unroll
    for (int mi = 0; mi < 4; ++mi)
#pragma unroll
      for (int ni = 0; ni < 2; ++ni) {
        int d = wn + ni * 16 + lmod;
        int s = m0 + wm + mi * 16 + lgrp * 4;
        uint2 o;
        o.x = pack2bf(acc[mi][ni][0], acc[mi][ni][1]);
        o.y = pack2bf(acc[mi][ni][2], acc[mi][ni][3]);
        *(uint2*)&Vt[((size_t)(kvh * 64 + d)) * 4096 + s] = o;
      }
    return;
  }

  const float qscale = 0.18033688011112042f;   // 0.125 * log2(e)
  const bool isQ = (cbase < 1024);
  const int h = isQ ? (cbase >> 6) : ((cbase - 1024) >> 6);
  unsigned short* dstbase = isQ ? Qh : Kh;
  const bool evn = (lmod & 1) == 0;
#pragma unroll
  for (int mi = 0; mi < 4; ++mi)
#pragma unroll
    for (int ni = 0; ni < 2; ++ni) {
      int d = ((cbase & 63) + wn + ni * 16 + lmod) & 63;   // = wn+ni*16+lmod
      int i = d >> 1;
#pragma unroll
      for (int r = 0; r < 4; ++r) {
        float v = acc[mi][ni][r];
        float pp = __shfl_xor(v, 1, 64);
        int rl = wm + mi * 16 + lgrp * 4 + r;
        float2 sc = scT[(size_t)(m0 + rl) * 32 + i];
        float e = evn ? v : pp, o = evn ? pp : v;
        float outv = evn ? (sc.y * e - sc.x * o) : (sc.x * e + sc.y * o);
        if (isQ) outv *= qscale;
        dstbase[((size_t)h * 4096 + m0 + rl) * 64 + d] = f2bf(outv);
      }
    }
}

// ---------------- out-proj GEMM: 128x64 tile, m97 2-barrier, f32 out ----------------
__global__ __launch_bounds__(256, 3) void gemm_out(const unsigned short* __restrict__ A,
                                                   const unsigned short* __restrict__ Bt,
                                                   float* __restrict__ Cout) {
  __shared__ __align__(16) unsigned short Als[128 * 32];
  __shared__ __align__(16) unsigned short Bls[64 * 32];
  const int K = 1024, N = 1024;
  const int tid = threadIdx.x;
  const int wave = tid >> 6, lane = tid & 63;
  const int lgrp = lane >> 4, lmod = lane & 15;
  const int wm = (wave & 1) * 64, wn = (wave >> 1) * 32;
  const int m0 = blockIdx.y * 128, n0 = blockIdx.x * 64;
  const int rr = tid >> 2, cc = (tid & 3) * 8;

  f32x4 acc[4][2] = {};

  for (int k0 = 0; k0 < K; k0 += 32) {
    __syncthreads();
#pragma unroll
    for (int it = 0; it < 2; ++it) {
      int idx = tid + it * 256;
      __builtin_amdgcn_global_load_lds((gas1)(const void*)&A[(size_t)(m0 + (idx >> 2)) * K + k0 + cc],
                                       (las3)(void*)&Als[(it * 256 + wave * 64) * 8], 16, 0, 0);
    }
    __builtin_amdgcn_global_load_lds((gas1)(const void*)&Bt[(size_t)(n0 + rr) * K + k0 + cc],
                                     (las3)(void*)&Bls[(wave * 64) * 8], 16, 0, 0);
    __syncthreads();
    bf16x8 af[4], bfr[2];
#pragma unroll
    for (int mi = 0; mi < 4; ++mi)
      af[mi] = __builtin_bit_cast(bf16x8, *(const u32x4*)&Als[(wm + mi * 16 + lmod) * 32 + lgrp * 8]);
#pragma unroll
    for (int ni = 0; ni < 2; ++ni)
      bfr[ni] = __builtin_bit_cast(bf16x8, *(const u32x4*)&Bls[(wn + ni * 16 + lmod) * 32 + lgrp * 8]);
#pragma unroll
    for (int mi = 0; mi < 4; ++mi)
#pragma unroll
      for (int ni = 0; ni < 2; ++ni)
        acc[mi][ni] = __builtin_amdgcn_mfma_f32_16x16x32_bf16(af[mi], bfr[ni], acc[mi][ni], 0, 0, 0);
  }

#pragma unroll
  for (int mi = 0; mi < 4; ++mi)
#pragma unroll
    for (int ni = 0; ni < 2; ++ni)
#pragma unroll
      for (int r = 0; r < 4; ++r) {
        int row = m0 + wm + mi * 16 + lgrp * 4 + r;
        int col = n0 + wn + ni * 16 + lmod;
        Cout[(size_t)row * N + col] = acc[mi][ni][r];
      }
}

// ---------------- Flash attention: attn3 body, 2-wave blocks, balanced static map ------
// grid 1024, block 128 (2 waves, 64 q-rows). qidx = bx>>4, head = bx&15.
// qb64 map: <16 -> 63-q, <32 -> 16+q, <48 -> 63-q, else q-48. Under XCD round-robin,
// each CU's 4 resident blocks sum to a constant 66 chunk-units.
__global__ __launch_bounds__(128, 4) void attn7(const unsigned short* __restrict__ Qh,
                                                const unsigned short* __restrict__ Kh,
                                                const unsigned short* __restrict__ Vt,
                                                unsigned short* __restrict__ ctx) {
  __shared__ __align__(16) unsigned short Kls[128 * 68];   // [key][d], stride 68
  __shared__ __align__(16) unsigned short Vls[64 * 136];   // [d][key], stride 136
  const int bx = blockIdx.x;
  const int head = bx & 15;
  const int qidx = bx >> 4;
  int qb64;
  if (qidx < 16)      qb64 = 63 - qidx;
  else if (qidx < 32) qb64 = 16 + qidx - 16 + 16;   // 16+q where q=qidx-16 -> 32..47
  else if (qidx < 48) qb64 = 63 - qidx;             // 31..16
  else                qb64 = qidx - 48;             // 0..15
  const int kvh = head >> 2;
  const int tid = threadIdx.x;
  const int wave = tid >> 6, lane = tid & 63;
  const int lgrp = lane >> 4, lmod = lane & 15;
  const int qbase = qb64 * 64;
  const int nch = (qb64 >> 1) + 1;

  const unsigned short* Kg = Kh + (size_t)kvh * 4096 * 64;
  const unsigned short* Vg = Vt + (size_t)kvh * 64 * 4096;

  bf16x8 qf[2][2];
  int qrow[2];
#pragma unroll
  for (int qt = 0; qt < 2; ++qt) {
    qrow[qt] = qbase + wave * 32 + qt * 16 + lmod;
    const unsigned short* Qg = Qh + ((size_t)head * 4096 + qrow[qt]) * 64;
    qf[qt][0] = __builtin_bit_cast(bf16x8, *(const u32x4*)&Qg[lgrp * 8]);
    qf[qt][1] = __builtin_bit_cast(bf16x8, *(const u32x4*)&Qg[32 + lgrp * 8]);
  }

  const int kbase = (8 * (lmod >> 2) + (lmod & 3)) * 68 + lgrp * 8;
  const int vbase = lmod * 136 + lgrp * 8;

  f32x4 accO[2][4] = {};
  float m_i[2] = {-3e38f, -3e38f}, l_i[2] = {0.f, 0.f};

  for (int kc = 0; kc < nch; ++kc) {
    const int kb = kc * 128;
    __syncthreads();
#pragma unroll
    for (int i = 0; i < 8; ++i) {
      int ii = tid + i * 128;
      int r = ii >> 3, sg = (ii & 7) * 8;
      u32x4 dK = *(const u32x4*)&Kg[(size_t)(kb + r) * 64 + sg];
      uint2* pd = (uint2*)&Kls[r * 68 + sg];
      pd[0] = make_uint2(dK[0], dK[1]);
      pd[1] = make_uint2(dK[2], dK[3]);
    }
#pragma unroll
    for (int i = 0; i < 8; ++i) {
      int ii = tid + i * 128;
      int r = ii >> 4, sg = (ii & 15) * 8;
      *(u32x4*)&Vls[r * 136 + sg] = *(const u32x4*)&Vg[(size_t)r * 4096 + kb + sg];
    }
    __syncthreads();

    f32x4 s[4][2][2];
#pragma unroll
    for (int g = 0; g < 4; ++g)
#pragma unroll
      for (int t = 0; t < 2; ++t) {
        const unsigned short* ka = &Kls[kbase + (32 * g + 4 * t) * 68];
        uint2 a0 = *(const uint2*)&ka[0];
        uint2 a1 = *(const uint2*)&ka[4];
        uint2 b0 = *(const uint2*)&ka[32];
        uint2 b1 = *(const uint2*)&ka[36];
        u32x4 lo = {a0.x, a0.y, a1.x, a1.y};
        u32x4 hi = {b0.x, b0.y, b1.x, b1.y};
        bf16x8 alo = __builtin_bit_cast(bf16x8, lo);
        bf16x8 ahi = __builtin_bit_cast(bf16x8, hi);
#pragma unroll
        for (int qt = 0; qt < 2; ++qt) {
          f32x4 z = {};
          z = __builtin_amdgcn_mfma_f32_16x16x32_bf16(alo, qf[qt][0], z, 0, 0, 0);
          z = __builtin_amdgcn_mfma_f32_16x16x32_bf16(ahi, qf[qt][1], z, 0, 0, 0);
          s[g][t][qt] = z;
        }
      }

#pragma unroll
    for (int qt = 0; qt < 2; ++qt) {
      if (kb + 127 > qbase + wave * 32 + qt * 16) {
#pragma unroll
        for (int g = 0; g < 4; ++g)
#pragma unroll
          for (int t = 0; t < 2; ++t)
#pragma unroll
            for (int r = 0; r < 4; ++r) {
              int key = kb + 32 * g + 8 * lgrp + 4 * t + r;
              if (key > qrow[qt]) s[g][t][qt][r] = -3e38f;
            }
      }
    }

#pragma unroll
    for (int qt = 0; qt < 2; ++qt) {
      f32x4 v0 = s[0][0][qt], v1 = s[0][1][qt];
#pragma unroll
      for (int g = 1; g < 4; ++g)
#pragma unroll
        for (int r = 0; r < 4; ++r) {
          v0[r] = fmaxf(v0[r], s[g][0][qt][r]);
          v1[r] = fmaxf(v1[r], s[g][1][qt][r]);
        }
      float mx = fmaxf(fmaxf(fmaxf(v0[0], v0[1]), fmaxf(v0[2], v0[3])),
                       fmaxf(fmaxf(v1[0], v1[1]), fmaxf(v1[2], v1[3])));
      mx = fmaxf(mx, __shfl_xor(mx, 16, 64));
      mx = fmaxf(mx, __shfl_xor(mx, 32, 64));
      float mnew = fmaxf(m_i[qt], mx);
      float alpha = __builtin_amdgcn_exp2f(m_i[qt] - mnew);
      m_i[qt] = mnew;
      f32x4 su = {};
#pragma unroll
      for (int g = 0; g < 4; ++g)
#pragma unroll
        for (int t = 0; t < 2; ++t)
#pragma unroll
          for (int r = 0; r < 4; ++r) {
            float ev = __builtin_amdgcn_exp2f(s[g][t][qt][r] - mnew);
            s[g][t][qt][r] = ev;
            su[r] += ev;
          }
      float rs = (su[0] + su[1]) + (su[2] + su[3]);
      rs += __shfl_xor(rs, 16, 64);
      rs += __shfl_xor(rs, 32, 64);
      l_i[qt] = l_i[qt] * alpha + rs;
#pragma unroll
      for (int dt = 0; dt < 4; ++dt)
#pragma unroll
        for (int r = 0; r < 4; ++r) accO[qt][dt][r] *= alpha;
    }

#pragma unroll
    for (int g = 0; g < 4; ++g) {
      bf16x8 pf[2];
#pragma unroll
      for (int qt = 0; qt < 2; ++qt) {
        u32x4 pk;
        pk[0] = packtr(s[g][0][qt][0], s[g][0][qt][1]);
        pk[1] = packtr(s[g][0][qt][2], s[g][0][qt][3]);
        pk[2] = packtr(s[g][1][qt][0], s[g][1][qt][1]);
        pk[3] = packtr(s[g][1][qt][2], s[g][1][qt][3]);
        pf[qt] = __builtin_bit_cast(bf16x8, pk);
      }
#pragma unroll
      for (int dt = 0; dt < 4; ++dt) {
        bf16x8 vf = __builtin_bit_cast(bf16x8, *(const u32x4*)&Vls[vbase + dt * 2176 + 32 * g]);
        accO[0][dt] = __builtin_amdgcn_mfma_f32_16x16x32_bf16(vf, pf[0], accO[0][dt], 0, 0, 0);
        accO[1][dt] = __builtin_amdgcn_mfma_f32_16x16x32_bf16(vf, pf[1], accO[1][dt], 0, 0, 0);
      }
    }
  }

#pragma unroll
  for (int qt = 0; qt < 2; ++qt) {
    float inv = 1.f / l_i[qt];
#pragma unroll
    for (int dt = 0; dt < 4; ++dt) {
      uint2 o;
      o.x = pack2bf(accO[qt][dt][0] * inv, accO[qt][dt][1] * inv);
      o.y = pack2bf(accO[qt][dt][2] * inv, accO[qt][dt][3] * inv);
      *(uint2*)&ctx[(size_t)qrow[qt] * 1024 + head * 64 + dt * 16 + lgrp * 4] = o;
    }
  }
}

extern "C" void kernel_launch(void* const* d_in, const int* in_sizes, int n_in,
                              void* d_out, int out_size, void* d_ws, size_t ws_size,
                              hipStream_t stream) {
  const float* x    = (const float*)d_in[0];
  const float* wq   = (const float*)d_in[3];
  const float* wk   = (const float*)d_in[4];
  const float* wv   = (const float*)d_in[5];
  const float* wo   = (const float*)d_in[6];
  const float* sinT = (const float*)d_in[7];
  const float* cosT = (const float*)d_in[8];

  unsigned short* ws    = (unsigned short*)d_ws;
  unsigned short* xb    = ws;                          // 4096*1024
  unsigned short* wtqkv = xb + 4096 * 1024;            // 1536*1024
  unsigned short* wot   = wtqkv + 1536 * 1024;         // 1024*1024
  unsigned short* Qh    = wot + 1024 * 1024;           // 16*4096*64
  unsigned short* Kh    = Qh + 16 * 4096 * 64;         // 4*4096*64
  unsigned short* Vt    = Kh + 4 * 4096 * 64;          // 4*64*4096
  unsigned short* ctx   = Vt + 4 * 64 * 4096;          // 4096*1024
  float2* scT           = (float2*)(ctx + 4096 * 1024);// 4096*32 float2 (1 MB)
  float* out = (float*)d_out;

  prep<<<7168, 256, 0, stream>>>(x, wq, wk, wv, wo, sinT, cosT, xb, wtqkv, wot, scT);
  gemm_qkv<<<dim3(24, 32), 256, 0, stream>>>(xb, wtqkv, scT, Qh, Kh, Vt);
  attn7<<<dim3(1024), 128, 0, stream>>>(Qh, Kh, Vt, ctx);
  gemm_out<<<dim3(16, 32), 256, 0, stream>>>(ctx, wot, out);
}

// Round 10
// 249.683 us; speedup vs baseline: 1.0777x; 1.0777x over previous
//
#include <hip/hip_runtime.h>

typedef __bf16 bf16x8 __attribute__((ext_vector_type(8)));
typedef float f32x4 __attribute__((ext_vector_type(4)));
typedef unsigned int u32x4 __attribute__((ext_vector_type(4)));

typedef const void __attribute__((address_space(1)))* gas1;
typedef void __attribute__((address_space(3)))* las3;

__device__ __forceinline__ unsigned short f2bf(float f) {
  unsigned int u = __builtin_bit_cast(unsigned int, f);
  u += 0x7fffu + ((u >> 16) & 1u);   // RNE
  return (unsigned short)(u >> 16);
}
__device__ __forceinline__ float bf2f(unsigned short h) {
  unsigned int u = ((unsigned int)h) << 16;
  return __builtin_bit_cast(float, u);
}
__device__ __forceinline__ unsigned int pack2bf(float lo, float hi) {
  return (unsigned int)f2bf(lo) | ((unsigned int)f2bf(hi) << 16);
}
// truncating pack (P in [0,1])
__device__ __forceinline__ unsigned int packtr(float lo, float hi) {
  return __builtin_amdgcn_perm(__builtin_bit_cast(unsigned int, hi),
                               __builtin_bit_cast(unsigned int, lo), 0x07060302u);
}

// ---------------- fused prep: x->bf16 + 4 weight transposes + packed sin/cos ----------
__global__ __launch_bounds__(256) void prep(const float* __restrict__ x,
                                            const float* __restrict__ wq,
                                            const float* __restrict__ wk,
                                            const float* __restrict__ wv,
                                            const float* __restrict__ wo,
                                            const float* __restrict__ sinT,
                                            const float* __restrict__ cosT,
                                            unsigned short* __restrict__ xb,
                                            unsigned short* __restrict__ wtqkv,
                                            unsigned short* __restrict__ wot,
                                            float2* __restrict__ scT) {
  __shared__ float tile[32][33];
  const int b = blockIdx.x;
  const int tid = threadIdx.x;
  if (b < 4096) {
    int i = b * 256 + tid;
    float4 v = ((const float4*)x)[i];
    uint2 o;
    o.x = pack2bf(v.x, v.y);
    o.y = pack2bf(v.z, v.w);
    ((uint2*)xb)[i] = o;
    return;
  }
  if (b >= 6656) {
    int idx = (b - 6656) * 256 + tid;    // 131072 = 4096*32
    scT[idx] = make_float2(sinT[idx], cosT[idx]);
    return;
  }
  const float* src;
  unsigned short* dst;
  int R, C, t;
  if (b < 5120)      { t = b - 4096; src = wq; dst = wtqkv;               R = 1024; C = 1024; }
  else if (b < 5376) { t = b - 5120; src = wk; dst = wtqkv + 1024 * 1024; R = 1024; C = 256; }
  else if (b < 5632) { t = b - 5376; src = wv; dst = wtqkv + 1280 * 1024; R = 1024; C = 256; }
  else               { t = b - 5632; src = wo; dst = wot;                 R = 1024; C = 1024; }
  const int ntc = C >> 5;
  const int c0 = (t % ntc) * 32, r0 = (t / ntc) * 32;
  const int tx = tid & 31, ty = tid >> 5;
#pragma unroll
  for (int i = 0; i < 4; ++i)
    tile[ty + i * 8][tx] = src[(r0 + ty + i * 8) * C + c0 + tx];
  __syncthreads();
#pragma unroll
  for (int i = 0; i < 4; ++i)
    dst[(c0 + ty + i * 8) * R + r0 + tx] = f2bf(tile[tx][ty + i * 8]);
}

// ---------------- QKV GEMM: 64x64 tile, ONE wave per block, BK=32 ----------------
// grid (24, 64): n-tile 0..15 Q (rope), 16..19 K (rope), 20..23 V (transposed store).
// 1-wave blocks: barrier = intra-wave only; 1536 blocks ≈ 6/CU hide all latency.
__global__ __launch_bounds__(64, 4) void gemm_qkv(const unsigned short* __restrict__ A,
                                                  const unsigned short* __restrict__ Bt,
                                                  const float2* __restrict__ scT,
                                                  unsigned short* __restrict__ Qh,
                                                  unsigned short* __restrict__ Kh,
                                                  unsigned short* __restrict__ Vt) {
  __shared__ __align__(16) unsigned short Als[64 * 32];
  __shared__ __align__(16) unsigned short Bls[64 * 32];
  const int K = 1024;
  const int lane = threadIdx.x;
  const int lgrp = lane >> 4, lmod = lane & 15;
  const int m0 = blockIdx.y * 64, n0 = blockIdx.x * 64;
  const int lr = lane >> 2, lc = (lane & 3) * 8;   // 16 rows x 32 cols per glds

  f32x4 acc[4][4] = {};

  for (int k0 = 0; k0 < K; k0 += 32) {
    __syncthreads();
#pragma unroll
    for (int i = 0; i < 4; ++i) {
      __builtin_amdgcn_global_load_lds((gas1)(const void*)&A[(size_t)(m0 + i * 16 + lr) * K + k0 + lc],
                                       (las3)(void*)&Als[i * 512], 16, 0, 0);
      __builtin_amdgcn_global_load_lds((gas1)(const void*)&Bt[(size_t)(n0 + i * 16 + lr) * K + k0 + lc],
                                       (las3)(void*)&Bls[i * 512], 16, 0, 0);
    }
    __syncthreads();
    bf16x8 af[4], bfr[4];
#pragma unroll
    for (int mi = 0; mi < 4; ++mi)
      af[mi] = __builtin_bit_cast(bf16x8, *(const u32x4*)&Als[(mi * 16 + lmod) * 32 + lgrp * 8]);
#pragma unroll
    for (int ni = 0; ni < 4; ++ni)
      bfr[ni] = __builtin_bit_cast(bf16x8, *(const u32x4*)&Bls[(ni * 16 + lmod) * 32 + lgrp * 8]);
#pragma unroll
    for (int mi = 0; mi < 4; ++mi)
#pragma unroll
      for (int ni = 0; ni < 4; ++ni)
        acc[mi][ni] = __builtin_amdgcn_mfma_f32_16x16x32_bf16(af[mi], bfr[ni], acc[mi][ni], 0, 0, 0);
  }

  if (n0 >= 1280) {
    // V: transposed store
    const int kvh = (n0 - 1280) >> 6;
#pragma unroll
    for (int mi = 0; mi < 4; ++mi)
#pragma unroll
      for (int ni = 0; ni < 4; ++ni) {
        int d = ni * 16 + lmod;
        int s = m0 + mi * 16 + lgrp * 4;
        uint2 o;
        o.x = pack2bf(acc[mi][ni][0], acc[mi][ni][1]);
        o.y = pack2bf(acc[mi][ni][2], acc[mi][ni][3]);
        *(uint2*)&Vt[((size_t)(kvh * 64 + d)) * 4096 + s] = o;
      }
    return;
  }

  const float qscale = 0.18033688011112042f;   // 0.125 * log2(e)
  const bool isQ = (n0 < 1024);
  const int h = isQ ? (n0 >> 6) : ((n0 - 1024) >> 6);
  unsigned short* dstbase = isQ ? Qh : Kh;
  const bool evn = (lmod & 1) == 0;
#pragma unroll
  for (int mi = 0; mi < 4; ++mi)
#pragma unroll
    for (int ni = 0; ni < 4; ++ni) {
      int d = ni * 16 + lmod;
      int i = d >> 1;
#pragma unroll
      for (int r = 0; r < 4; ++r) {
        float v = acc[mi][ni][r];
        float pp = __shfl_xor(v, 1, 64);
        int rl = mi * 16 + lgrp * 4 + r;
        float2 sc = scT[(size_t)(m0 + rl) * 32 + i];
        float e = evn ? v : pp, o = evn ? pp : v;
        float outv = evn ? (sc.y * e - sc.x * o) : (sc.x * e + sc.y * o);
        if (isQ) outv *= qscale;
        dstbase[((size_t)h * 4096 + m0 + rl) * 64 + d] = f2bf(outv);
      }
    }
}

// ---------------- out-proj GEMM: 64x64 tile, ONE wave per block, f32 out ----------------
__global__ __launch_bounds__(64, 4) void gemm_out(const unsigned short* __restrict__ A,
                                                  const unsigned short* __restrict__ Bt,
                                                  float* __restrict__ Cout) {
  __shared__ __align__(16) unsigned short Als[64 * 32];
  __shared__ __align__(16) unsigned short Bls[64 * 32];
  const int K = 1024, N = 1024;
  const int lane = threadIdx.x;
  const int lgrp = lane >> 4, lmod = lane & 15;
  const int m0 = blockIdx.y * 64, n0 = blockIdx.x * 64;
  const int lr = lane >> 2, lc = (lane & 3) * 8;

  f32x4 acc[4][4] = {};

  for (int k0 = 0; k0 < K; k0 += 32) {
    __syncthreads();
#pragma unroll
    for (int i = 0; i < 4; ++i) {
      __builtin_amdgcn_global_load_lds((gas1)(const void*)&A[(size_t)(m0 + i * 16 + lr) * K + k0 + lc],
                                       (las3)(void*)&Als[i * 512], 16, 0, 0);
      __builtin_amdgcn_global_load_lds((gas1)(const void*)&Bt[(size_t)(n0 + i * 16 + lr) * K + k0 + lc],
                                       (las3)(void*)&Bls[i * 512], 16, 0, 0);
    }
    __syncthreads();
    bf16x8 af[4], bfr[4];
#pragma unroll
    for (int mi = 0; mi < 4; ++mi)
      af[mi] = __builtin_bit_cast(bf16x8, *(const u32x4*)&Als[(mi * 16 + lmod) * 32 + lgrp * 8]);
#pragma unroll
    for (int ni = 0; ni < 4; ++ni)
      bfr[ni] = __builtin_bit_cast(bf16x8, *(const u32x4*)&Bls[(ni * 16 + lmod) * 32 + lgrp * 8]);
#pragma unroll
    for (int mi = 0; mi < 4; ++mi)
#pragma unroll
      for (int ni = 0; ni < 4; ++ni)
        acc[mi][ni] = __builtin_amdgcn_mfma_f32_16x16x32_bf16(af[mi], bfr[ni], acc[mi][ni], 0, 0, 0);
  }

#pragma unroll
  for (int mi = 0; mi < 4; ++mi)
#pragma unroll
    for (int ni = 0; ni < 4; ++ni)
#pragma unroll
      for (int r = 0; r < 4; ++r) {
        int row = m0 + mi * 16 + lgrp * 4 + r;
        int col = n0 + ni * 16 + lmod;
        Cout[(size_t)row * N + col] = acc[mi][ni][r];
      }
}

// ---------------- Flash attention: attn3 (R3/R6 verbatim, 82 us) ----------------
__global__ __launch_bounds__(256, 2) void attn3(const unsigned short* __restrict__ Qh,
                                                const unsigned short* __restrict__ Kh,
                                                const unsigned short* __restrict__ Vt,
                                                unsigned short* __restrict__ ctx) {
  __shared__ __align__(16) unsigned short Kls[128 * 68];   // [key][d], stride 68
  __shared__ __align__(16) unsigned short Vls[64 * 136];   // [d][key], stride 136
  const int bx = blockIdx.x;
  const int head = bx & 15;
  const int qidx = bx >> 4;
  const int qb = (qidx < 16) ? (31 - qidx) : (qidx - 16);
  const int kvh = head >> 2;
  const int tid = threadIdx.x;
  const int wave = tid >> 6, lane = tid & 63;
  const int lgrp = lane >> 4, lmod = lane & 15;
  const int qbase = qb * 128;

  const unsigned short* Kg = Kh + (size_t)kvh * 4096 * 64;
  const unsigned short* Vg = Vt + (size_t)kvh * 64 * 4096;

  bf16x8 qf[2][2];
  int qrow[2];
#pragma unroll
  for (int qt = 0; qt < 2; ++qt) {
    qrow[qt] = qbase + wave * 32 + qt * 16 + lmod;
    const unsigned short* Qg = Qh + ((size_t)head * 4096 + qrow[qt]) * 64;
    qf[qt][0] = __builtin_bit_cast(bf16x8, *(const u32x4*)&Qg[lgrp * 8]);
    qf[qt][1] = __builtin_bit_cast(bf16x8, *(const u32x4*)&Qg[32 + lgrp * 8]);
  }

  const int kbase = (8 * (lmod >> 2) + (lmod & 3)) * 68 + lgrp * 8;
  const int vbase = lmod * 136 + lgrp * 8;

  f32x4 accO[2][4] = {};
  float m_i[2] = {-3e38f, -3e38f}, l_i[2] = {0.f, 0.f};

  for (int kc = 0; kc <= qb; ++kc) {
    const int kb = kc * 128;
    __syncthreads();
#pragma unroll
    for (int i = 0; i < 4; ++i) {
      int ii = tid + i * 256;
      int r = ii >> 3, sg = (ii & 7) * 8;
      u32x4 dK = *(const u32x4*)&Kg[(size_t)(kb + r) * 64 + sg];
      uint2* pd = (uint2*)&Kls[r * 68 + sg];
      pd[0] = make_uint2(dK[0], dK[1]);
      pd[1] = make_uint2(dK[2], dK[3]);
    }
#pragma unroll
    for (int i = 0; i < 4; ++i) {
      int ii = tid + i * 256;
      int r = ii >> 4, sg = (ii & 15) * 8;
      *(u32x4*)&Vls[r * 136 + sg] = *(const u32x4*)&Vg[(size_t)r * 4096 + kb + sg];
    }
    __syncthreads();

    f32x4 s[4][2][2];
#pragma unroll
    for (int g = 0; g < 4; ++g)
#pragma unroll
      for (int t = 0; t < 2; ++t) {
        const unsigned short* ka = &Kls[kbase + (32 * g + 4 * t) * 68];
        uint2 a0 = *(const uint2*)&ka[0];
        uint2 a1 = *(const uint2*)&ka[4];
        uint2 b0 = *(const uint2*)&ka[32];
        uint2 b1 = *(const uint2*)&ka[36];
        u32x4 lo = {a0.x, a0.y, a1.x, a1.y};
        u32x4 hi = {b0.x, b0.y, b1.x, b1.y};
        bf16x8 alo = __builtin_bit_cast(bf16x8, lo);
        bf16x8 ahi = __builtin_bit_cast(bf16x8, hi);
#pragma unroll
        for (int qt = 0; qt < 2; ++qt) {
          f32x4 z = {};
          z = __builtin_amdgcn_mfma_f32_16x16x32_bf16(alo, qf[qt][0], z, 0, 0, 0);
          z = __builtin_amdgcn_mfma_f32_16x16x32_bf16(ahi, qf[qt][1], z, 0, 0, 0);
          s[g][t][qt] = z;
        }
      }

#pragma unroll
    for (int qt = 0; qt < 2; ++qt) {
      if (kb + 127 > qbase + wave * 32 + qt * 16) {
#pragma unroll
        for (int g = 0; g < 4; ++g)
#pragma unroll
          for (int t = 0; t < 2; ++t)
#pragma unroll
            for (int r = 0; r < 4; ++r) {
              int key = kb + 32 * g + 8 * lgrp + 4 * t + r;
              if (key > qrow[qt]) s[g][t][qt][r] = -3e38f;
            }
      }
    }

#pragma unroll
    for (int qt = 0; qt < 2; ++qt) {
      f32x4 v0 = s[0][0][qt], v1 = s[0][1][qt];
#pragma unroll
      for (int g = 1; g < 4; ++g)
#pragma unroll
        for (int r = 0; r < 4; ++r) {
          v0[r] = fmaxf(v0[r], s[g][0][qt][r]);
          v1[r] = fmaxf(v1[r], s[g][1][qt][r]);
        }
      float mx = fmaxf(fmaxf(fmaxf(v0[0], v0[1]), fmaxf(v0[2], v0[3])),
                       fmaxf(fmaxf(v1[0], v1[1]), fmaxf(v1[2], v1[3])));
      mx = fmaxf(mx, __shfl_xor(mx, 16, 64));
      mx = fmaxf(mx, __shfl_xor(mx, 32, 64));
      float mnew = fmaxf(m_i[qt], mx);
      float alpha = __builtin_amdgcn_exp2f(m_i[qt] - mnew);
      m_i[qt] = mnew;
      f32x4 su = {};
#pragma unroll
      for (int g = 0; g < 4; ++g)
#pragma unroll
        for (int t = 0; t < 2; ++t)
#pragma unroll
          for (int r = 0; r < 4; ++r) {
            float ev = __builtin_amdgcn_exp2f(s[g][t][qt][r] - mnew);
            s[g][t][qt][r] = ev;
            su[r] += ev;
          }
      float rs = (su[0] + su[1]) + (su[2] + su[3]);
      rs += __shfl_xor(rs, 16, 64);
      rs += __shfl_xor(rs, 32, 64);
      l_i[qt] = l_i[qt] * alpha + rs;
#pragma unroll
      for (int dt = 0; dt < 4; ++dt)
#pragma unroll
        for (int r = 0; r < 4; ++r) accO[qt][dt][r] *= alpha;
    }

#pragma unroll
    for (int g = 0; g < 4; ++g) {
      bf16x8 pf[2];
#pragma unroll
      for (int qt = 0; qt < 2; ++qt) {
        u32x4 pk;
        pk[0] = packtr(s[g][0][qt][0], s[g][0][qt][1]);
        pk[1] = packtr(s[g][0][qt][2], s[g][0][qt][3]);
        pk[2] = packtr(s[g][1][qt][0], s[g][1][qt][1]);
        pk[3] = packtr(s[g][1][qt][2], s[g][1][qt][3]);
        pf[qt] = __builtin_bit_cast(bf16x8, pk);
      }
#pragma unroll
      for (int dt = 0; dt < 4; ++dt) {
        bf16x8 vf = __builtin_bit_cast(bf16x8, *(const u32x4*)&Vls[vbase + dt * 2176 + 32 * g]);
        accO[0][dt] = __builtin_amdgcn_mfma_f32_16x16x32_bf16(vf, pf[0], accO[0][dt], 0, 0, 0);
        accO[1][dt] = __builtin_amdgcn_mfma_f32_16x16x32_bf16(vf, pf[1], accO[1][dt], 0, 0, 0);
      }
    }
  }

#pragma unroll
  for (int qt = 0; qt < 2; ++qt) {
    float inv = 1.f / l_i[qt];
#pragma unroll
    for (int dt = 0; dt < 4; ++dt) {
      uint2 o;
      o.x = pack2bf(accO[qt][dt][0] * inv, accO[qt][dt][1] * inv);
      o.y = pack2bf(accO[qt][dt][2] * inv, accO[qt][dt][3] * inv);
      *(uint2*)&ctx[(size_t)qrow[qt] * 1024 + head * 64 + dt * 16 + lgrp * 4] = o;
    }
  }
}

extern "C" void kernel_launch(void* const* d_in, const int* in_sizes, int n_in,
                              void* d_out, int out_size, void* d_ws, size_t ws_size,
                              hipStream_t stream) {
  const float* x    = (const float*)d_in[0];
  const float* wq   = (const float*)d_in[3];
  const float* wk   = (const float*)d_in[4];
  const float* wv   = (const float*)d_in[5];
  const float* wo   = (const float*)d_in[6];
  const float* sinT = (const float*)d_in[7];
  const float* cosT = (const float*)d_in[8];

  unsigned short* ws    = (unsigned short*)d_ws;
  unsigned short* xb    = ws;                          // 4096*1024
  unsigned short* wtqkv = xb + 4096 * 1024;            // 1536*1024
  unsigned short* wot   = wtqkv + 1536 * 1024;         // 1024*1024
  unsigned short* Qh    = wot + 1024 * 1024;           // 16*4096*64
  unsigned short* Kh    = Qh + 16 * 4096 * 64;         // 4*4096*64
  unsigned short* Vt    = Kh + 4 * 4096 * 64;          // 4*64*4096
  unsigned short* ctx   = Vt + 4 * 64 * 4096;          // 4096*1024
  float2* scT           = (float2*)(ctx + 4096 * 1024);// 4096*32 float2
  float* out = (float*)d_out;

  prep<<<7168, 256, 0, stream>>>(x, wq, wk, wv, wo, sinT, cosT, xb, wtqkv, wot, scT);
  gemm_qkv<<<dim3(24, 64), 64, 0, stream>>>(xb, wtqkv, scT, Qh, Kh, Vt);
  attn3<<<dim3(512), 256, 0, stream>>>(Qh, Kh, Vt, ctx);
  gemm_out<<<dim3(16, 64), 64, 0, stream>>>(ctx, wot, out);
}